// Round 6
// baseline (283.311 us; speedup 1.0000x reference)
//
#include <hip/hip_runtime.h>

// L=4096, N=B=64. CH=8 -> CN=512 chunks; GC=16 chunks/group -> NG=32 groups.
#define TL 4096
#define NB 64
#define CH 8
#define CN 512
#define GC 16
#define NG 32
#define AS 72          // LDS row stride (bf16 elems) for K1/K4

typedef __attribute__((ext_vector_type(8))) short short8;
typedef __attribute__((ext_vector_type(4))) short short4v;
typedef __attribute__((ext_vector_type(4))) float floatx4;

__device__ inline floatx4 mfma_bf16(short8 a, short8 b, floatx4 c) {
    return __builtin_amdgcn_mfma_f32_16x16x32_bf16(a, b, c, 0, 0, 0);
}

// fp32 -> (hi, lo) bf16 pair, RNE both. x ~= hi + lo to ~2^-17 rel.
__device__ inline void split_bf16(float x, short& h, short& l) {
    union { float f; unsigned u; } v; v.f = x;
    unsigned uh = v.u + 0x7FFFu + ((v.u >> 16) & 1u);
    h = (short)(uh >> 16);
    union { unsigned u; float f; } hv; hv.u = ((unsigned)(unsigned short)h) << 16;
    float r = x - hv.f;
    union { float f; unsigned u; } rv; rv.f = r;
    unsigned ul = rv.u + 0x7FFFu + ((rv.u >> 16) & 1u);
    l = (short)(ul >> 16);
}

// C-layout accumulator (4 tiles over rows, own col l15) -> B-operand frag for
// k-chunk kc. Target lane (quad,l15), j: k=32kc+8q+j comes from
// acc[2kc + ((8q+j)>>4)][j&3] on lane ((2q+(j>>2))&3)*16 + l15.
// Pure intra-wave shuffles; index algebra verified for all q,j,kc.
__device__ inline void cvt_CtoB(const floatx4* acc, int kc, int quad, int l15,
                                short8& bh, short8& bl)
{
#pragma unroll
    for (int j = 0; j < 8; ++j) {
        int srcl = (((2*quad + (j>>2)) & 3) << 4) + l15;
        float vlo = __shfl(acc[2*kc][j&3], srcl);
        float vhi = __shfl(acc[2*kc+1][j&3], srcl);
        float v = (quad >= 2) ? vhi : vlo;
        short hh, ll; split_bf16(v, hh, ll);
        bh[j] = hh; bl[j] = ll;
    }
}

// ---------------------------------------------------------------------------
// K1 (phase1): per chunk c, forward S <- A[t] S, V <- A[t] V + u_t.
// Emits PT[c]=S^T fp32 ([entry][exit]), VT[c]=V^T fp32 ([b][state]), and
// PRh/PRl = S pre-split bf16 row-major [exit][entry] (A-frags for K2).
// ---------------------------------------------------------------------------
__global__ __launch_bounds__(256, 2)
void hippo_phase1(const float* __restrict__ inp, const float* __restrict__ Ag,
                  const float* __restrict__ Bst,
                  float* __restrict__ PT, float* __restrict__ VT,
                  unsigned short* __restrict__ PRh, unsigned short* __restrict__ PRl)
{
    __shared__ short Ah[NB][AS], Al[NB][AS];
    __shared__ short SBh[NB][AS], SBl[NB][AS];
    __shared__ short VBh[NB][AS], VBl[NB][AS];
    __shared__ float btl[NB], itl[NB];

    const int tid  = threadIdx.x;
    const int c    = blockIdx.x;
    const int t0   = c * CH;
    const int w    = tid >> 6, lane = tid & 63;
    const int quad = lane >> 4, l15 = lane & 15;

#pragma unroll
    for (int q = 0; q < 16; ++q) {
        int f = tid + q * 256;
        int n = f >> 6, k = f & 63;
        SBh[n][k] = (n == k) ? (short)0x3F80 : (short)0;
        SBl[n][k] = 0; VBh[n][k] = 0; VBl[n][k] = 0;
    }

    float4 pre[4];
    {
        const float4* Ap = (const float4*)(Ag + (size_t)t0 * 4096);
#pragma unroll
        for (int q = 0; q < 4; ++q) pre[q] = Ap[tid + q * 256];
    }
    floatx4 accS[4], accV[4];

    for (int s = 0; s < CH; ++s) {
        int t = t0 + s;
#pragma unroll
        for (int q = 0; q < 4; ++q) {
            int f = tid + q * 256;
            int m = f >> 4, k0 = (f & 15) * 4;
            float vv[4] = {pre[q].x, pre[q].y, pre[q].z, pre[q].w};
            short4v h4, l4;
#pragma unroll
            for (int r = 0; r < 4; ++r) { short hh, ll; split_bf16(vv[r], hh, ll); h4[r]=hh; l4[r]=ll; }
            *(short4v*)&Ah[m][k0] = h4;
            *(short4v*)&Al[m][k0] = l4;
        }
        if (tid < 64) { btl[tid] = Bst[(size_t)t*64 + tid]; itl[tid] = inp[(size_t)t*64 + tid]; }
        if (s + 1 < CH) {
            const float4* Ap = (const float4*)(Ag + (size_t)(t+1) * 4096);
#pragma unroll
            for (int q = 0; q < 4; ++q) pre[q] = Ap[tid + q * 256];
        }
        __syncthreads();

#pragma unroll
        for (int ni = 0; ni < 4; ++ni) {
            float ib = itl[16*ni + l15];
#pragma unroll
            for (int r = 0; r < 4; ++r) {
                accS[ni][r] = 0.0f;
                accV[ni][r] = btl[16*w + 4*quad + r] * ib;
            }
        }
#pragma unroll
        for (int kc = 0; kc < 2; ++kc) {
            int ko = 32*kc + 8*quad;
            short8 aH = *(const short8*)&Ah[16*w + l15][ko];
            short8 aL = *(const short8*)&Al[16*w + l15][ko];
#pragma unroll
            for (int ni = 0; ni < 4; ++ni) {
                int n = 16*ni + l15;
                short8 sH = *(const short8*)&SBh[n][ko];
                short8 sL = *(const short8*)&SBl[n][ko];
                accS[ni] = mfma_bf16(aH, sH, accS[ni]);
                accS[ni] = mfma_bf16(aH, sL, accS[ni]);
                accS[ni] = mfma_bf16(aL, sH, accS[ni]);
                short8 vH = *(const short8*)&VBh[n][ko];
                short8 vL = *(const short8*)&VBl[n][ko];
                accV[ni] = mfma_bf16(aH, vH, accV[ni]);
                accV[ni] = mfma_bf16(aH, vL, accV[ni]);
                accV[ni] = mfma_bf16(aL, vH, accV[ni]);
            }
        }
        __syncthreads();

        if (s + 1 < CH) {
#pragma unroll
            for (int ni = 0; ni < 4; ++ni) {
                int cc = 16*ni + l15, r0 = 16*w + 4*quad;
                short4v h4, l4;
#pragma unroll
                for (int r = 0; r < 4; ++r) { short hh,ll; split_bf16(accS[ni][r],hh,ll); h4[r]=hh; l4[r]=ll; }
                *(short4v*)&SBh[cc][r0] = h4; *(short4v*)&SBl[cc][r0] = l4;
#pragma unroll
                for (int r = 0; r < 4; ++r) { short hh,ll; split_bf16(accV[ni][r],hh,ll); h4[r]=hh; l4[r]=ll; }
                *(short4v*)&VBh[cc][r0] = h4; *(short4v*)&VBl[cc][r0] = l4;
            }
            __syncthreads();
        }
    }
#pragma unroll
    for (int ni = 0; ni < 4; ++ni) {
        int cc = 16*ni + l15, r0 = 16*w + 4*quad;
        *(floatx4*)(PT + (size_t)c*4096 + cc*64 + r0) = accS[ni];
        *(floatx4*)(VT + (size_t)c*4096 + cc*64 + r0) = accV[ni];
        // pre-split row-major [exit][entry] copy for K2's direct A-frags
#pragma unroll
        for (int r = 0; r < 4; ++r) {
            short hh, ll; split_bf16(accS[ni][r], hh, ll);
            size_t o = (size_t)c*4096 + (size_t)(r0 + r)*64 + cc;
            PRh[o] = (unsigned short)hh; PRl[o] = (unsigned short)ll;
        }
    }
}

// ---------------------------------------------------------------------------
// K2 (barrier-free): NG WGs, 4 waves each; wave owns 16 columns of both the
// P-chain (entry cols) and V-chain (batch cols). No LDS, no __syncthreads.
// Overwrites PT[c]/VT[c] with the EXCLUSIVE in-group prefix (j>=1).
// Totals: GPh/GPl bf16 row-major [exit][entry], GV fp32 [b][state].
// ---------------------------------------------------------------------------
__global__ __launch_bounds__(256, 1)
void hippo_groupscan(float* __restrict__ PT, float* __restrict__ VT,
                     const unsigned short* __restrict__ PRh,
                     const unsigned short* __restrict__ PRl,
                     unsigned short* __restrict__ GPh,
                     unsigned short* __restrict__ GPl,
                     float* __restrict__ GV)
{
    const int g = blockIdx.x, tid = threadIdx.x;
    const int w = tid>>6, lane = tid&63, quad = lane>>4, l15 = lane&15;
    const int col = 16*w + l15;
    const int c0 = g * GC;

    floatx4 accP[4], accV[4];
#pragma unroll
    for (int mi = 0; mi < 4; ++mi) {
        accP[mi] = *(const floatx4*)(PT + (size_t)c0*4096 + col*64 + 16*mi + 4*quad);
        accV[mi] = *(const floatx4*)(VT + (size_t)c0*4096 + col*64 + 16*mi + 4*quad);
    }

    for (int j = 1; j < GC; ++j) {
        const int c = c0 + j;
        // A-frags of P_c: direct pre-split loads (chain-independent)
        short8 aH[4][2], aL[4][2];
#pragma unroll
        for (int mi = 0; mi < 4; ++mi)
#pragma unroll
            for (int kc = 0; kc < 2; ++kc) {
                size_t off = (size_t)c*4096 + (size_t)(16*mi + l15)*64 + 32*kc + 8*quad;
                aH[mi][kc] = *(const short8*)(PRh + off);
                aL[mi][kc] = *(const short8*)(PRl + off);
            }
        floatx4 vc[4];
#pragma unroll
        for (int mi = 0; mi < 4; ++mi)
            vc[mi] = *(const floatx4*)(VT + (size_t)c*4096 + col*64 + 16*mi + 4*quad);

        // B-frags from carried state (pure shuffles, no memory)
        short8 bPh[2], bPl[2], bVh[2], bVl[2];
#pragma unroll
        for (int kc = 0; kc < 2; ++kc) {
            cvt_CtoB(accP, kc, quad, l15, bPh[kc], bPl[kc]);
            cvt_CtoB(accV, kc, quad, l15, bVh[kc], bVl[kc]);
        }

        floatx4 nP[4], nV[4];
#pragma unroll
        for (int mi = 0; mi < 4; ++mi) {
            nV[mi] = vc[mi];
            nP[mi][0]=0.f; nP[mi][1]=0.f; nP[mi][2]=0.f; nP[mi][3]=0.f;
        }
#pragma unroll
        for (int kc = 0; kc < 2; ++kc)
#pragma unroll
            for (int mi = 0; mi < 4; ++mi) {
                nP[mi] = mfma_bf16(aH[mi][kc], bPh[kc], nP[mi]);
                nP[mi] = mfma_bf16(aH[mi][kc], bPl[kc], nP[mi]);
                nP[mi] = mfma_bf16(aL[mi][kc], bPh[kc], nP[mi]);
                nV[mi] = mfma_bf16(aH[mi][kc], bVh[kc], nV[mi]);
                nV[mi] = mfma_bf16(aH[mi][kc], bVl[kc], nV[mi]);
                nV[mi] = mfma_bf16(aL[mi][kc], bVh[kc], nV[mi]);
            }
        // exclusive-prefix in-place stores. Safe AFTER the MFMAs: the MFMA
        // consumed vc, so the vc load has completed before VT[c] is overwritten.
#pragma unroll
        for (int mi = 0; mi < 4; ++mi) {
            *(floatx4*)(PT + (size_t)c*4096 + col*64 + 16*mi + 4*quad) = accP[mi];
            *(floatx4*)(VT + (size_t)c*4096 + col*64 + 16*mi + 4*quad) = accV[mi];
        }
#pragma unroll
        for (int mi = 0; mi < 4; ++mi) { accP[mi] = nP[mi]; accV[mi] = nV[mi]; }
    }
    // group totals
#pragma unroll
    for (int mi = 0; mi < 4; ++mi) {
        *(floatx4*)(GV + (size_t)g*4096 + col*64 + 16*mi + 4*quad) = accV[mi];
#pragma unroll
        for (int r = 0; r < 4; ++r) {
            short hh, ll; split_bf16(accP[mi][r], hh, ll);
            size_t o = (size_t)g*4096 + (size_t)(16*mi + 4*quad + r)*64 + col;
            GPh[o] = (unsigned short)hh; GPl[o] = (unsigned short)ll;
        }
    }
}

// ---------------------------------------------------------------------------
// K3 (barrier-free): 1 WG, 4 independent column-waves.
// E <- GP[g] @ E + GV[g]; EgT[g] = inclusive prefix, fp32 [b][state].
// A-frags direct from pre-split GPh/GPl, prefetched one step ahead.
// ---------------------------------------------------------------------------
__global__ __launch_bounds__(256, 1)
void hippo_superscan(const unsigned short* __restrict__ GPh,
                     const unsigned short* __restrict__ GPl,
                     const float* __restrict__ GV, float* __restrict__ EgT)
{
    const int tid = threadIdx.x;
    const int w = tid>>6, lane = tid&63, quad = lane>>4, l15 = lane&15;
    const int col = 16*w + l15;

    floatx4 accE[4];
#pragma unroll
    for (int mi = 0; mi < 4; ++mi) {
        accE[mi] = *(const floatx4*)(GV + col*64 + 16*mi + 4*quad);
        *(floatx4*)(EgT + col*64 + 16*mi + 4*quad) = accE[mi];
    }
    short8 aHc[4][2], aLc[4][2]; floatx4 gvc[4];
#pragma unroll
    for (int mi = 0; mi < 4; ++mi) {
#pragma unroll
        for (int kc = 0; kc < 2; ++kc) {
            size_t off = (size_t)4096 + (size_t)(16*mi + l15)*64 + 32*kc + 8*quad;
            aHc[mi][kc] = *(const short8*)(GPh + off);
            aLc[mi][kc] = *(const short8*)(GPl + off);
        }
        gvc[mi] = *(const floatx4*)(GV + (size_t)4096 + col*64 + 16*mi + 4*quad);
    }

    for (int g = 1; g < NG; ++g) {
        short8 aHn[4][2], aLn[4][2]; floatx4 gvn[4];
        if (g + 1 < NG) {
#pragma unroll
            for (int mi = 0; mi < 4; ++mi) {
#pragma unroll
                for (int kc = 0; kc < 2; ++kc) {
                    size_t off = (size_t)(g+1)*4096 + (size_t)(16*mi + l15)*64 + 32*kc + 8*quad;
                    aHn[mi][kc] = *(const short8*)(GPh + off);
                    aLn[mi][kc] = *(const short8*)(GPl + off);
                }
                gvn[mi] = *(const floatx4*)(GV + (size_t)(g+1)*4096 + col*64 + 16*mi + 4*quad);
            }
        }
        short8 bh[2], bl[2];
#pragma unroll
        for (int kc = 0; kc < 2; ++kc) cvt_CtoB(accE, kc, quad, l15, bh[kc], bl[kc]);

        floatx4 nE[4];
#pragma unroll
        for (int mi = 0; mi < 4; ++mi) nE[mi] = gvc[mi];
#pragma unroll
        for (int kc = 0; kc < 2; ++kc)
#pragma unroll
            for (int mi = 0; mi < 4; ++mi) {
                nE[mi] = mfma_bf16(aHc[mi][kc], bh[kc], nE[mi]);
                nE[mi] = mfma_bf16(aHc[mi][kc], bl[kc], nE[mi]);
                nE[mi] = mfma_bf16(aLc[mi][kc], bh[kc], nE[mi]);
            }
#pragma unroll
        for (int mi = 0; mi < 4; ++mi) {
            accE[mi] = nE[mi];
            *(floatx4*)(EgT + (size_t)g*4096 + col*64 + 16*mi + 4*quad) = accE[mi];
        }
        if (g + 1 < NG) {
#pragma unroll
            for (int mi = 0; mi < 4; ++mi) {
#pragma unroll
                for (int kc = 0; kc < 2; ++kc) { aHc[mi][kc] = aHn[mi][kc]; aLc[mi][kc] = aLn[mi][kc]; }
                gvc[mi] = gvn[mi];
            }
        }
    }
}

// ---------------------------------------------------------------------------
// K4 (phase3 + entry, unchanged from R4/R5 proven version).
// ---------------------------------------------------------------------------
__global__ __launch_bounds__(256, 2)
void hippo_phase3(const float* __restrict__ inp, const float* __restrict__ Ag,
                  const float* __restrict__ Bst,
                  const float* __restrict__ PeT, const float* __restrict__ VeT,
                  const float* __restrict__ EgT, float* __restrict__ out)
{
    __shared__ short Ah[NB][AS], Al[NB][AS];
    __shared__ short XBh[NB][AS], XBl[NB][AS];
    __shared__ short EBh[NB][AS], EBl[NB][AS];
    __shared__ float btl[NB], itl[NB];

    const int tid = threadIdx.x, c = blockIdx.x, t0 = c * CH;
    const int g = c >> 4, j = c & (GC - 1);
    const int w = tid>>6, lane = tid&63, quad = lane>>4, l15 = lane&15;

    float4 pre[4];
    {
        const float4* Ap = (const float4*)(Ag + (size_t)t0 * 4096);
#pragma unroll
        for (int q = 0; q < 4; ++q) pre[q] = Ap[tid + q * 256];
    }

    if (c == 0) {
#pragma unroll
        for (int q = 0; q < 16; ++q) { int f = tid + q*256; XBh[f>>6][f&63] = 0; XBl[f>>6][f&63] = 0; }
    } else if (j == 0 || g == 0) {
        const float* e = (j == 0) ? (EgT + (size_t)(g-1)*4096) : (VeT + (size_t)c*4096);
#pragma unroll
        for (int q = 0; q < 4; ++q) {
            int f = tid + q*256; int b = f>>4, k0 = (f&15)*4;
            float4 v = *(const float4*)(e + b*64 + k0);
            float va[4] = {v.x,v.y,v.z,v.w};
            short4v h4, l4;
#pragma unroll
            for (int r=0;r<4;++r){short hh,ll;split_bf16(va[r],hh,ll);h4[r]=hh;l4[r]=ll;}
            *(short4v*)&XBh[b][k0] = h4; *(short4v*)&XBl[b][k0] = l4;
        }
    } else {
        const float* pe = PeT + (size_t)c*4096;
        const float* eg = EgT + (size_t)(g-1)*4096;
#pragma unroll
        for (int q = 0; q < 4; ++q) {
            int f = tid + q*256;
            int k = f & 63, m0 = (f >> 6) * 4;
            float4 v = *(const float4*)(pe + k*64 + m0);
            float vv[4] = {v.x,v.y,v.z,v.w};
#pragma unroll
            for (int rr=0;rr<4;++rr){short hh,ll;split_bf16(vv[rr],hh,ll);Ah[m0+rr][k]=hh;Al[m0+rr][k]=ll;}
        }
#pragma unroll
        for (int q = 0; q < 4; ++q) {
            int f = tid + q*256; int b = f>>4, k0 = (f&15)*4;
            float4 v = *(const float4*)(eg + b*64 + k0);
            float va[4] = {v.x,v.y,v.z,v.w};
            short4v h4, l4;
#pragma unroll
            for (int r=0;r<4;++r){short hh,ll;split_bf16(va[r],hh,ll);h4[r]=hh;l4[r]=ll;}
            *(short4v*)&EBh[b][k0] = h4; *(short4v*)&EBl[b][k0] = l4;
        }
        __syncthreads();
        const float* ve = VeT + (size_t)c*4096;
        floatx4 ax[4];
#pragma unroll
        for (int ni = 0; ni < 4; ++ni) {
            int cc = 16*ni + l15, r0 = 16*w + 4*quad;
            ax[ni] = *(const floatx4*)(ve + cc*64 + r0);
        }
#pragma unroll
        for (int kc = 0; kc < 2; ++kc) {
            int ko = 32*kc + 8*quad;
            short8 aH = *(const short8*)&Ah[16*w + l15][ko];
            short8 aL = *(const short8*)&Al[16*w + l15][ko];
#pragma unroll
            for (int ni = 0; ni < 4; ++ni) {
                int n = 16*ni + l15;
                short8 eH = *(const short8*)&EBh[n][ko];
                short8 eL = *(const short8*)&EBl[n][ko];
                ax[ni] = mfma_bf16(aH,eH,ax[ni]);
                ax[ni] = mfma_bf16(aH,eL,ax[ni]);
                ax[ni] = mfma_bf16(aL,eH,ax[ni]);
            }
        }
        __syncthreads();
#pragma unroll
        for (int ni = 0; ni < 4; ++ni) {
            int cc = 16*ni + l15, r0 = 16*w + 4*quad;
            short4v h4, l4;
#pragma unroll
            for (int r=0;r<4;++r){short hh,ll;split_bf16(ax[ni][r],hh,ll);h4[r]=hh;l4[r]=ll;}
            *(short4v*)&XBh[cc][r0] = h4; *(short4v*)&XBl[cc][r0] = l4;
        }
    }

    floatx4 acc[4];
    for (int s = 0; s < CH; ++s) {
        int t = t0 + s;
#pragma unroll
        for (int q = 0; q < 4; ++q) {
            int f = tid + q*256; int m = f>>4, k0 = (f&15)*4;
            float vv[4] = {pre[q].x,pre[q].y,pre[q].z,pre[q].w};
            short4v h4, l4;
#pragma unroll
            for (int r=0;r<4;++r){short hh,ll;split_bf16(vv[r],hh,ll);h4[r]=hh;l4[r]=ll;}
            *(short4v*)&Ah[m][k0] = h4; *(short4v*)&Al[m][k0] = l4;
        }
        if (tid < 64) { btl[tid] = Bst[(size_t)t*64 + tid]; itl[tid] = inp[(size_t)t*64 + tid]; }
        if (s + 1 < CH) {
            const float4* Ap = (const float4*)(Ag + (size_t)(t+1) * 4096);
#pragma unroll
            for (int q = 0; q < 4; ++q) pre[q] = Ap[tid + q * 256];
        }
        __syncthreads();

#pragma unroll
        for (int ni = 0; ni < 4; ++ni) {
            float ib = itl[16*ni + l15];
#pragma unroll
            for (int r = 0; r < 4; ++r) acc[ni][r] = btl[16*w + 4*quad + r] * ib;
        }
#pragma unroll
        for (int kc = 0; kc < 2; ++kc) {
            int ko = 32*kc + 8*quad;
            short8 aH = *(const short8*)&Ah[16*w + l15][ko];
            short8 aL = *(const short8*)&Al[16*w + l15][ko];
#pragma unroll
            for (int ni = 0; ni < 4; ++ni) {
                int n = 16*ni + l15;
                short8 xH = *(const short8*)&XBh[n][ko];
                short8 xL = *(const short8*)&XBl[n][ko];
                acc[ni] = mfma_bf16(aH, xH, acc[ni]);
                acc[ni] = mfma_bf16(aH, xL, acc[ni]);
                acc[ni] = mfma_bf16(aL, xH, acc[ni]);
            }
        }
        __syncthreads();
#pragma unroll
        for (int ni = 0; ni < 4; ++ni) {
            int cc = 16*ni + l15, r0 = 16*w + 4*quad;
            *(floatx4*)(out + (size_t)t*4096 + cc*64 + r0) = acc[ni];
            if (s + 1 < CH) {
                short4v h4, l4;
#pragma unroll
                for (int r=0;r<4;++r){short hh,ll;split_bf16(acc[ni][r],hh,ll);h4[r]=hh;l4[r]=ll;}
                *(short4v*)&XBh[cc][r0] = h4; *(short4v*)&XBl[cc][r0] = l4;
            }
        }
        if (s + 1 < CH) __syncthreads();
    }
}

extern "C" void kernel_launch(void* const* d_in, const int* in_sizes, int n_in,
                              void* d_out, int out_size, void* d_ws, size_t ws_size,
                              hipStream_t stream)
{
    const float* inp = (const float*)d_in[0];   // (L, B)
    const float* A   = (const float*)d_in[1];   // (L, N, N)
    const float* Bst = (const float*)d_in[2];   // (L, N)
    float* out = (float*)d_out;                  // (L, B, N)
    char* ws = (char*)d_ws;                      // ~25.6 MB used

    float*          PT  = (float*)ws;                                  // 8 MB
    float*          VT  = (float*)(ws + (size_t)8*1024*1024);          // 8 MB
    unsigned short* PRh = (unsigned short*)(ws + (size_t)16*1024*1024);// 4 MB
    unsigned short* PRl = (unsigned short*)(ws + (size_t)20*1024*1024);// 4 MB
    unsigned short* GPh = (unsigned short*)(ws + (size_t)24*1024*1024);// 256 KB
    unsigned short* GPl = (unsigned short*)(ws + (size_t)24*1024*1024 + 256*1024);
    float*          GV  = (float*)(ws + (size_t)24*1024*1024 + 512*1024);   // 512 KB
    float*          EgT = (float*)(ws + (size_t)25*1024*1024);              // 512 KB

    hippo_phase1<<<CN, 256, 0, stream>>>(inp, A, Bst, PT, VT, PRh, PRl);
    hippo_groupscan<<<NG, 256, 0, stream>>>(PT, VT, PRh, PRl, GPh, GPl, GV);
    hippo_superscan<<<1, 256, 0, stream>>>(GPh, GPl, GV, EgT);
    hippo_phase3<<<CN, 256, 0, stream>>>(inp, A, Bst, PT, VT, EgT, out);
}